// Round 13
// baseline (281.873 us; speedup 1.0000x reference)
//
#include <hip/hip_runtime.h>
#include <hip/hip_bf16.h>
#include <math.h>

// R23: qkv -> 256x256 8-phase-style pipelined kernel (T3+T4). Unified theory
// from the R11-R22 ledger: all GEMMs are STAGING-TRAFFIC bound; intensity =
// BM*BN/(BM+BN) = 64 FLOP/byte at 128^2 -> qkv stages 786MB through L2/L3,
// ~45us floor (matches 83-96 with latency exposure). 256^2 halves traffic
// (128 F/B) but R19 proved it needs intra-block pipelining (depth-1 + 
// 2-barrier drain = 117us). This kernel: 16 K-tiles, 2 LDS buffers (128KB),
// 4 phases/tile, per phase {vmcnt-gate(ph0, counted 2, never 0 mid-loop) ->
// s_barrier -> stage ONE 16KB half-tile (2x global_load_lds) -> ds_read
// group (12/4/8/0 plan) -> 16 MFMA quadrant}. Hazards: reads of a buffer
// finish by ph2 -> ph3's same-buffer stage (t+2 A-lo) is WAR-safe behind
// its barrier; cross-buffer stages >=2 barriers behind last reader; each
// phase's ds_reads consumed by same-phase MFMA (lgkm-drained). Per-(i,j)
// accumulate order unchanged -> bitwise-identical. Raw s_barrier asm (no
// __syncthreads vmcnt(0) drain in loop). scores/pv/softmax/cvt = R22
// byte-identical. Pre-commit: pass & qkv>=85 -> refuted, finalize R22.
// LDS swizzle (verified, conflicts=0): row holds 8 chunks, phys p at row r
// = logical p^(r&7); staging pre-swizzles GLOBAL chunk ((t&7)^(trow&7)),
// LDS dest linear (= base+lane*16, m104); read phys = (quad^(kk<<2))^(l16&7).

typedef __bf16 bf16x8 __attribute__((ext_vector_type(8)));
typedef float  f32x4  __attribute__((ext_vector_type(4)));

__device__ __forceinline__ ushort f2bf(float f) {
    __hip_bfloat16 h = __float2bfloat16(f);
    return *reinterpret_cast<ushort*>(&h);
}

__device__ __forceinline__ void async_load16(const ushort* g, ushort* l) {
    __builtin_amdgcn_global_load_lds(
        (const __attribute__((address_space(1))) void*)g,
        (__attribute__((address_space(3))) void*)l, 16, 0, 0);
}

// One launch for all 4 fp32->bf16 conversions + RoPE cos/sin table.
// grid (8192, 5): y<4 = conversions, y==4 = table gen (first 4096 x-blocks).
__global__ __launch_bounds__(256) void cvt_all_kernel(
    const float* __restrict__ x,  const float* __restrict__ wq,
    const float* __restrict__ wk, const float* __restrict__ wv,
    ushort* __restrict__ xb, ushort* __restrict__ wqb,
    ushort* __restrict__ wkb, ushort* __restrict__ wvb,
    float2* __restrict__ cs)
{
    const int t = blockIdx.y;
    if (t == 4) {
        // cs[pos*512 + i] = (cos(pos*phi_i), sin(pos*phi_i)),
        // phi_i = 10000^(-2*(i-1)/1024)  (reference's -1 quirk preserved).
        const int idx = blockIdx.x * 256 + threadIdx.x;
        if (idx < 2048 * 512) {
            const int pos = idx >> 9, i = idx & 511;
            const float phi = powf(10000.0f, -2.0f * ((float)i - 1.0f) / 1024.0f);
            float s, c;
            sincosf((float)pos * phi, &s, &c);
            cs[idx] = make_float2(c, s);
        }
        return;
    }
    const float* in  = (t == 0) ? x  : (t == 1) ? wq  : (t == 2) ? wk  : wv;
    ushort*      out = (t == 0) ? xb : (t == 1) ? wqb : (t == 2) ? wkb : wvb;
    const int n4 = (t == 0) ? 2097152 : 262144;
    int i = blockIdx.x * blockDim.x + threadIdx.x;
    if (i < n4) {
        float4 f = ((const float4*)in)[i];
        ushort4 o;
        o.x = f2bf(f.x); o.y = f2bf(f.y); o.z = f2bf(f.z); o.w = f2bf(f.w);
        ((ushort4*)out)[i] = o;
    }
}

// ------------- double-buffered BK=64 core: scores/pv (R22) ----------------
// LDS: As/Bs each [2][128][64] ushort (32 KB each, 64 KB total).
__device__ __forceinline__ void gemm128_core_db64(
    const ushort* __restrict__ A, const ushort* __restrict__ B,
    int lda, int ldb, int m0, int n0, int kIters,
    ushort* As, ushort* Bs, f32x4 acc[4][4])
{
    const int tid  = threadIdx.x;
    const int lane = tid & 63, wave = tid >> 6;
    const int wm = (wave >> 1) * 64, wn = (wave & 1) * 64;
    const int quad = lane >> 4, l16 = lane & 15;
    const int srow8 = lane >> 3;
    const int gchk  = (lane & 7) ^ srow8;
    const ushort* ag = A + (size_t)(m0 + wave * 32 + srow8) * lda + gchk * 8;
    const ushort* bg = B + (size_t)(n0 + wave * 32 + srow8) * ldb + gchk * 8;
    const int p0 = quad ^ (l16 & 7);

#define STAGE64(K0, NB) do {                                            \
        _Pragma("unroll")                                               \
        for (int s = 0; s < 4; ++s) {                                   \
            async_load16(ag + (K0) + (size_t)(s * 8) * lda,             \
                         As + (NB) + (wave * 32 + s * 8) * 64);         \
            async_load16(bg + (K0) + (size_t)(s * 8) * ldb,             \
                         Bs + (NB) + (wave * 32 + s * 8) * 64);         \
        }                                                               \
    } while (0)

    STAGE64(0, 0);
    __syncthreads();

    int cur = 0;
    for (int kt = 0; kt < kIters; ++kt) {
        if (kt + 1 < kIters) STAGE64((kt + 1) * 64, (cur ^ 1) * 8192);
        const ushort* as = As + cur * 8192;
        const ushort* bs = Bs + cur * 8192;
#pragma unroll
        for (int kk = 0; kk < 2; ++kk) {
            const int poff = (p0 ^ (kk << 2)) * 8;
            bf16x8 aF[4], bF[4];
#pragma unroll
            for (int i = 0; i < 4; ++i)
                aF[i] = *(const bf16x8*)(as + (wm + i * 16 + l16) * 64 + poff);
#pragma unroll
            for (int j = 0; j < 4; ++j)
                bF[j] = *(const bf16x8*)(bs + (wn + j * 16 + l16) * 64 + poff);
#pragma unroll
            for (int i = 0; i < 4; ++i)
#pragma unroll
                for (int j = 0; j < 4; ++j)
                    acc[i][j] = __builtin_amdgcn_mfma_f32_16x16x32_bf16(aF[i], bF[j], acc[i][j], 0, 0, 0);
        }
        __syncthreads();
        cur ^= 1;
    }
#undef STAGE64
}

#define ACC_INIT4(acc) \
    _Pragma("unroll") for (int i = 0; i < 4; ++i) \
    _Pragma("unroll") for (int j = 0; j < 4; ++j) \
    _Pragma("unroll") for (int r = 0; r < 4; ++r) acc[i][j][r] = 0.0f;

// QKV + RoPE: 256x256 tile, 8 waves (per-wave 128x64), BK=64, 4-phase
// pipelined K-loop with counted vmcnt. grid (32, 4, 3), 512 threads.
__global__ __launch_bounds__(512) void qkv_rope_kernel(
    const ushort* __restrict__ xb, const ushort* __restrict__ wq,
    const ushort* __restrict__ wk, const ushort* __restrict__ wv,
    const float2* __restrict__ cs,
    ushort* __restrict__ Qr, ushort* __restrict__ Kr, ushort* __restrict__ VT)
{
    __shared__ __attribute__((aligned(16))) ushort As[2 * 256 * 64];  // 64 KB
    __shared__ __attribute__((aligned(16))) ushort Bs[2 * 256 * 64];  // 64 KB
    const int m0 = blockIdx.x * 256;
    const int n0 = blockIdx.y * 256;
    const int z  = blockIdx.z;
    const ushort* W = (z == 0) ? wq : (z == 1) ? wk : wv;

    const int tid  = threadIdx.x;
    const int lane = tid & 63, wave = tid >> 6;
    const int wm = (wave >> 2) * 128;          // 2 wave-rows of 128
    const int wn = (wave & 3) * 64;            // 4 wave-cols of 64
    const int quad = lane >> 4, l16 = lane & 15;

    // Staging map (512 threads cover 64 rows x 64 cols per load inst):
    // thread t: row trow = t>>3 (+64 for 2nd load), chunk (t&7), global
    // chunk pre-swizzled (t&7)^(trow&7). LDS dest linear = base + lane*16.
    const int trow = tid >> 3;                 // 0..63
    const int gchk = (tid & 7) ^ (trow & 7);
    const ushort* ag = xb + (size_t)(m0 + trow) * 1024 + gchk * 8;
    const ushort* bg = W  + (size_t)(n0 + trow) * 1024 + gchk * 8;
    const int ldst = trow * 64 + (tid & 7) * 8;

    // Stage one 16KB half-tile (128 rows) of tile TAU, half HALF (0=lo,1=hi).
#define STGH(gb, Ls, TAU, HALF) do {                                        \
        const int _k0 = (TAU) * 64;                                         \
        ushort* _d = (Ls) + ((TAU) & 1) * 16384 + (HALF) * 8192 + ldst;     \
        async_load16((gb) + (size_t)((HALF) * 128) * 1024 + _k0, _d);       \
        async_load16((gb) + (size_t)((HALF) * 128 + 64) * 1024 + _k0, _d + 4096); \
    } while (0)

    f32x4 acc[8][4];
#pragma unroll
    for (int i = 0; i < 8; ++i)
#pragma unroll
        for (int j = 0; j < 4; ++j)
#pragma unroll
            for (int r = 0; r < 4; ++r) acc[i][j][r] = 0.0f;

    // Prologue: tile0 all 4 halves + tile1 A-lo (10 loads/thread-pair).
    STGH(ag, As, 0, 0); STGH(ag, As, 0, 1);
    STGH(bg, Bs, 0, 0); STGH(bg, Bs, 0, 1);
    STGH(ag, As, 1, 0);

    const int p0 = quad ^ (l16 & 7);
    bf16x8 aF[8], bF0[4], bF1[4];   // aF: current m-group x 2kk; bF: n-groups

    for (int t = 0; t < 16; ++t) {
        const ushort* as = As + (t & 1) * 16384;
        const ushort* bs = Bs + (t & 1) * 16384;
        // ---- ph0: gate + stage A-hi(t+1) + read A[mg0],B[ng0] + MFMA ----
        if (t < 15) asm volatile("s_waitcnt vmcnt(2)" ::: "memory");
        else        asm volatile("s_waitcnt vmcnt(0)" ::: "memory");
        asm volatile("s_barrier" ::: "memory");
        if (t + 1 < 16) STGH(ag, As, t + 1, 1);
#pragma unroll
        for (int ii = 0; ii < 4; ++ii)
#pragma unroll
            for (int kk = 0; kk < 2; ++kk)
                aF[ii * 2 + kk] = *(const bf16x8*)(as + (wm + ii * 16 + l16) * 64 + (p0 ^ (kk << 2)) * 8);
#pragma unroll
        for (int j = 0; j < 2; ++j)
#pragma unroll
            for (int kk = 0; kk < 2; ++kk)
                bF0[j * 2 + kk] = *(const bf16x8*)(bs + (wn + j * 16 + l16) * 64 + (p0 ^ (kk << 2)) * 8);
#pragma unroll
        for (int ii = 0; ii < 4; ++ii)
#pragma unroll
            for (int j = 0; j < 2; ++j)
#pragma unroll
                for (int kk = 0; kk < 2; ++kk)
                    acc[ii][j] = __builtin_amdgcn_mfma_f32_16x16x32_bf16(aF[ii * 2 + kk], bF0[j * 2 + kk], acc[ii][j], 0, 0, 0);
        // ---- ph1: stage B-lo(t+1) + read B[ng1] + MFMA mg0 x ng1 ----
        asm volatile("s_barrier" ::: "memory");
        if (t + 1 < 16) STGH(bg, Bs, t + 1, 0);
#pragma unroll
        for (int j = 0; j < 2; ++j)
#pragma unroll
            for (int kk = 0; kk < 2; ++kk)
                bF1[j * 2 + kk] = *(const bf16x8*)(bs + (wn + (j + 2) * 16 + l16) * 64 + (p0 ^ (kk << 2)) * 8);
#pragma unroll
        for (int ii = 0; ii < 4; ++ii)
#pragma unroll
            for (int j = 0; j < 2; ++j)
#pragma unroll
                for (int kk = 0; kk < 2; ++kk)
                    acc[ii][j + 2] = __builtin_amdgcn_mfma_f32_16x16x32_bf16(aF[ii * 2 + kk], bF1[j * 2 + kk], acc[ii][j + 2], 0, 0, 0);
        // ---- ph2: stage B-hi(t+1) + read A[mg1] + MFMA mg1 x ng1 ----
        asm volatile("s_barrier" ::: "memory");
        if (t + 1 < 16) STGH(bg, Bs, t + 1, 1);
#pragma unroll
        for (int ii = 0; ii < 4; ++ii)
#pragma unroll
            for (int kk = 0; kk < 2; ++kk)
                aF[ii * 2 + kk] = *(const bf16x8*)(as + (wm + (ii + 4) * 16 + l16) * 64 + (p0 ^ (kk << 2)) * 8);
#pragma unroll
        for (int ii = 0; ii < 4; ++ii)
#pragma unroll
            for (int j = 0; j < 2; ++j)
#pragma unroll
                for (int kk = 0; kk < 2; ++kk)
                    acc[ii + 4][j + 2] = __builtin_amdgcn_mfma_f32_16x16x32_bf16(aF[ii * 2 + kk], bF1[j * 2 + kk], acc[ii + 4][j + 2], 0, 0, 0);
        // ---- ph3: stage A-lo(t+2) + MFMA mg1 x ng0 (no reads) ----
        asm volatile("s_barrier" ::: "memory");
        if (t + 2 < 16) STGH(ag, As, t + 2, 0);
#pragma unroll
        for (int ii = 0; ii < 4; ++ii)
#pragma unroll
            for (int j = 0; j < 2; ++j)
#pragma unroll
                for (int kk = 0; kk < 2; ++kk)
                    acc[ii + 4][j] = __builtin_amdgcn_mfma_f32_16x16x32_bf16(aF[ii * 2 + kk], bF0[j * 2 + kk], acc[ii + 4][j], 0, 0, 0);
    }
#undef STGH

    // Epilogue (R19-verified layout: 8 m-frags x 4 n-frags per wave).
    if (z < 2) {
        ushort* out = (z == 0) ? Qr : Kr;
#pragma unroll
        for (int j = 0; j < 4; ++j) {
            const int n = n0 + wn + j * 16 + l16;
            const int iidx = n >> 1;
            const bool odd = n & 1;
#pragma unroll
            for (int i = 0; i < 8; ++i) {
                const int mbase = m0 + wm + i * 16 + quad * 4;
                const int pos0  = mbase & 2047;
                const float2* csp = cs + (size_t)pos0 * 512 + iidx;
#pragma unroll
                for (int r = 0; r < 4; ++r) {
                    const float2 sc = csp[(size_t)r * 512]; // (cos, sin) at pos0+r
                    float v = acc[i][j][r];
                    float p = __shfl_xor(v, 1);   // partner column n^1, same row
                    float o = odd ? (v * sc.x - p * sc.y) : (v * sc.x + p * sc.y);
                    out[(size_t)(mbase + r) * 1024 + n] = f2bf(o);
                }
            }
        }
    } else {
        // V transposed: VT[b][n][pos]; 4 consecutive pos per quad -> ushort4
#pragma unroll
        for (int i = 0; i < 8; ++i) {
            const int mbase = m0 + wm + i * 16 + quad * 4;
            const int b = mbase >> 11, pos0 = mbase & 2047;
#pragma unroll
            for (int j = 0; j < 4; ++j) {
                const int n = n0 + wn + j * 16 + l16;
                ushort4 o;
                o.x = f2bf(acc[i][j][0]); o.y = f2bf(acc[i][j][1]);
                o.z = f2bf(acc[i][j][2]); o.w = f2bf(acc[i][j][3]);
                *(ushort4*)(VT + ((size_t)b * 1024 + n) * 2048 + pos0) = o;
            }
        }
    }
}

// scores: grid (16, 16, 4); lower tiles only; S fp32 scaled 1/32. db64 core.
__global__ __launch_bounds__(256) void scores_kernel(
    const ushort* __restrict__ Qr, const ushort* __restrict__ Kr,
    float* __restrict__ S)
{
    const int m0 = blockIdx.x * 128;
    const int n0 = blockIdx.y * 128;
    if (n0 > m0 + 127) return;
    const int b = blockIdx.z;
    __shared__ __attribute__((aligned(16))) ushort As[2 * 128 * 64];
    __shared__ __attribute__((aligned(16))) ushort Bs[2 * 128 * 64];
    const ushort* A = Qr + (size_t)b * 2048 * 1024;
    const ushort* B = Kr + (size_t)b * 2048 * 1024;
    float* Sb = S + (size_t)b * 2048 * 2048;

    f32x4 acc[4][4];
    ACC_INIT4(acc)
    gemm128_core_db64(A, B, 1024, 1024, m0, n0, 16, As, Bs, acc);

    const int lane = threadIdx.x & 63, wave = threadIdx.x >> 6;
    const int wm = (wave >> 1) * 64, wn = (wave & 1) * 64;
    const int quad = lane >> 4, l16 = lane & 15;
#pragma unroll
    for (int i = 0; i < 4; ++i)
#pragma unroll
        for (int j = 0; j < 4; ++j) {
            const int n = n0 + wn + j * 16 + l16;
#pragma unroll
            for (int r = 0; r < 4; ++r) {
                const int m = m0 + wm + i * 16 + quad * 4 + r;
                Sb[(size_t)m * 2048 + n] = acc[i][j][r] * 0.03125f;
            }
        }
}

// Row softmax, register-staged, wave-parallel reduction (3 barriers).
// Reads clipped to nvalid; writes clipped to roundup(row+1,128).
__global__ __launch_bounds__(256) void softmax_kernel(
    const float* __restrict__ S, ushort* __restrict__ P)
{
    __shared__ float red[4];
    const int row = blockIdx.x, tid = threadIdx.x, b = blockIdx.y;
    const int lane = tid & 63, wave = tid >> 6;
    const float* s = S + ((size_t)b * 2048 + row) * 2048;
    ushort*      p = P + ((size_t)b * 2048 + row) * 2048;
    const int nvalid = row + 1;
    const int wlimit = (row & ~127) + 128;
    const int j0 = tid * 8;

    float v[8] = {0.0f, 0.0f, 0.0f, 0.0f, 0.0f, 0.0f, 0.0f, 0.0f};
    if (j0 < nvalid) {
        float4 f0 = *(const float4*)(s + j0);
        v[0]=f0.x; v[1]=f0.y; v[2]=f0.z; v[3]=f0.w;
    }
    if (j0 + 4 < nvalid) {
        float4 f1 = *(const float4*)(s + j0 + 4);
        v[4]=f1.x; v[5]=f1.y; v[6]=f1.z; v[7]=f1.w;
    }

    float mx = -3.402823466e38f;
#pragma unroll
    for (int u = 0; u < 8; ++u) if (j0 + u < nvalid) mx = fmaxf(mx, v[u]);
#pragma unroll
    for (int d = 1; d < 64; d <<= 1) mx = fmaxf(mx, __shfl_xor(mx, d));
    if (lane == 0) red[wave] = mx;
    __syncthreads();
    mx = fmaxf(fmaxf(red[0], red[1]), fmaxf(red[2], red[3]));

    float sum = 0.0f;
#pragma unroll
    for (int u = 0; u < 8; ++u) {
        v[u] = (j0 + u < nvalid) ? __expf(v[u] - mx) : 0.0f;
        sum += v[u];
    }
#pragma unroll
    for (int d = 1; d < 64; d <<= 1) sum += __shfl_xor(sum, d);
    __syncthreads();                 // all reads of red done before overwrite
    if (lane == 0) red[wave] = sum;
    __syncthreads();
    const float inv = 1.0f / (red[0] + red[1] + red[2] + red[3]);

    if (j0 < wlimit) {
        ushort o[8];
#pragma unroll
        for (int u = 0; u < 8; ++u) o[u] = f2bf(v[u] * inv);
        *(int4*)(p + j0) = *(const int4*)o;
    }
}

// pv: grid (16, 8, 4); causal k-limit; db64 core; m-tile interleave.
__global__ __launch_bounds__(256) void pv_kernel(
    const ushort* __restrict__ P, const ushort* __restrict__ VT,
    float* __restrict__ out)
{
    __shared__ __attribute__((aligned(16))) ushort As[2 * 128 * 64];
    __shared__ __attribute__((aligned(16))) ushort Bs[2 * 128 * 64];
    const int x  = blockIdx.x;
    const int mt = (x & 1) ? (15 - (x >> 1)) : (x >> 1);  // 0,15,1,14,...
    const int m0 = mt * 128;
    const int n0 = blockIdx.y * 128;
    const int b  = blockIdx.z;
    const ushort* A = P + (size_t)b * 2048 * 2048;
    const ushort* B = VT + (size_t)b * 1024 * 2048;
    const int kIters = (m0 + 128) / 64;   // causal: P[m][k]=0 for k>m

    f32x4 acc[4][4];
    ACC_INIT4(acc)
    gemm128_core_db64(A, B, 2048, 2048, m0, n0, kIters, As, Bs, acc);

    const int lane = threadIdx.x & 63, wave = threadIdx.x >> 6;
    const int wm = (wave >> 1) * 64, wn = (wave & 1) * 64;
    const int quad = lane >> 4, l16 = lane & 15;
#pragma unroll
    for (int i = 0; i < 4; ++i)
#pragma unroll
        for (int j = 0; j < 4; ++j) {
            const int n = n0 + wn + j * 16 + l16;
#pragma unroll
            for (int r = 0; r < 4; ++r) {
                const int m = m0 + wm + i * 16 + quad * 4 + r;
                out[((size_t)b * 2048 + m) * 1024 + n] = acc[i][j][r];
            }
        }
}

extern "C" void kernel_launch(void* const* d_in, const int* in_sizes, int n_in,
                              void* d_out, int out_size, void* d_ws, size_t ws_size,
                              hipStream_t stream) {
    const float* x  = (const float*)d_in[0];
    const float* wq = (const float*)d_in[1];
    const float* wk = (const float*)d_in[2];
    const float* wv = (const float*)d_in[3];

    const size_t MiB = 1024 * 1024;
    char* ws = (char*)d_ws;
    ushort* xb  = (ushort*)(ws);              //  16 MiB [8192][1024] bf16
    ushort* wqb = (ushort*)(ws +  16 * MiB);  //   2 MiB
    ushort* wkb = (ushort*)(ws +  18 * MiB);  //   2 MiB
    ushort* wvb = (ushort*)(ws +  20 * MiB);  //   2 MiB
    ushort* Qr  = (ushort*)(ws +  22 * MiB);  //  16 MiB [4][2048][1024] bf16
    ushort* Kr  = (ushort*)(ws +  38 * MiB);  //  16 MiB
    ushort* VT  = (ushort*)(ws +  54 * MiB);  //  16 MiB [4][1024][2048] bf16
    float*  S   = (float* )(ws +  70 * MiB);  //  64 MiB [4][2048][2048] f32
    ushort* P   = (ushort*)(ws + 134 * MiB);  //  32 MiB [4][2048][2048] bf16
    float2* cs  = (float2*)(ws + 166 * MiB);  //   8 MiB [2048][512] (cos,sin) f32
    float*  out = (float*)d_out;              // ws use: 174 MiB (256 avail)

    cvt_all_kernel <<<dim3(8192, 5),   256, 0, stream>>>(x, wq, wk, wv, xb, wqb, wkb, wvb, cs);
    qkv_rope_kernel<<<dim3(32, 4, 3),  512, 0, stream>>>(xb, wqb, wkb, wvb, cs, Qr, Kr, VT);
    scores_kernel  <<<dim3(16, 16, 4), 256, 0, stream>>>(Qr, Kr, S);
    softmax_kernel <<<dim3(2048, 4),   256, 0, stream>>>(S, P);
    pv_kernel      <<<dim3(16, 8, 4),  256, 0, stream>>>(P, VT, out);
}

// Round 14
// 260.057 us; speedup vs baseline: 1.0839x; 1.0839x over previous
//
#include <hip/hip_runtime.h>
#include <hip/hip_bf16.h>
#include <math.h>

// R24 FINAL: restore R22/R17 byte-identical (session best, 257.4-258.5us).
// R23 post-mortem: 4-phase 256^2 pipelined qkv refuted (123us, MfmaUtil 16%;
// traffic DID drop 57->47.6MB as the intensity math predicted, but 128KB LDS
// -> 1 block/CU and 4 barriers/K-tile x 8 waves exposed more sync than the
// 2-barrier loop it replaced). Two reconstruction attempts of the 8-phase
// family (R19 structure, R23 schedule) both failed -> negative EV to retry.
// Session: 296 -> ~258 via trig-table (R11, -7), core-split+pv-interleave
// (R13, -10), BK=64 barrier-halving (R17, -17). Refuted with evidence:
// dbuf/ring/counted-vmcnt on 2-phase loops (R12/R14), split-K depth
// (R18/R20), XCD chunk-swizzle (R21: FETCH 57->208MB), 256^2@depth-1
// (R19/R23). Plateau = 2-barrier 128^2 family's staging-latency bound
// (MfmaUtil 21-25%), not a HW roofline.
// Config: cvt+cos/sin table; qkv sb64 BK=64 grid(64,8,3); scores db64
// full-K grid(16,16,4) early-return; softmax single-S wave-parallel with
// read/write clip; pv db64 + m-interleave, causal k-limit.
// LDS swizzle (verified, conflicts=0): row holds 8 chunks, phys p at row r
// = logical p^(r&7); staging pre-swizzles GLOBAL chunk ((l&7)^(l>>3)), LDS
// dest linear (m104/m173); read phys = (quad^(kk<<2))^(l16&7).

typedef __bf16 bf16x8 __attribute__((ext_vector_type(8)));
typedef float  f32x4  __attribute__((ext_vector_type(4)));

__device__ __forceinline__ ushort f2bf(float f) {
    __hip_bfloat16 h = __float2bfloat16(f);
    return *reinterpret_cast<ushort*>(&h);
}

__device__ __forceinline__ void async_load16(const ushort* g, ushort* l) {
    __builtin_amdgcn_global_load_lds(
        (const __attribute__((address_space(1))) void*)g,
        (__attribute__((address_space(3))) void*)l, 16, 0, 0);
}

// One launch for all 4 fp32->bf16 conversions + RoPE cos/sin table.
// grid (8192, 5): y<4 = conversions, y==4 = table gen (first 4096 x-blocks).
__global__ __launch_bounds__(256) void cvt_all_kernel(
    const float* __restrict__ x,  const float* __restrict__ wq,
    const float* __restrict__ wk, const float* __restrict__ wv,
    ushort* __restrict__ xb, ushort* __restrict__ wqb,
    ushort* __restrict__ wkb, ushort* __restrict__ wvb,
    float2* __restrict__ cs)
{
    const int t = blockIdx.y;
    if (t == 4) {
        // cs[pos*512 + i] = (cos(pos*phi_i), sin(pos*phi_i)),
        // phi_i = 10000^(-2*(i-1)/1024)  (reference's -1 quirk preserved).
        const int idx = blockIdx.x * 256 + threadIdx.x;
        if (idx < 2048 * 512) {
            const int pos = idx >> 9, i = idx & 511;
            const float phi = powf(10000.0f, -2.0f * ((float)i - 1.0f) / 1024.0f);
            float s, c;
            sincosf((float)pos * phi, &s, &c);
            cs[idx] = make_float2(c, s);
        }
        return;
    }
    const float* in  = (t == 0) ? x  : (t == 1) ? wq  : (t == 2) ? wk  : wv;
    ushort*      out = (t == 0) ? xb : (t == 1) ? wqb : (t == 2) ? wkb : wvb;
    const int n4 = (t == 0) ? 2097152 : 262144;
    int i = blockIdx.x * blockDim.x + threadIdx.x;
    if (i < n4) {
        float4 f = ((const float4*)in)[i];
        ushort4 o;
        o.x = f2bf(f.x); o.y = f2bf(f.y); o.z = f2bf(f.z); o.w = f2bf(f.w);
        ((ushort4*)out)[i] = o;
    }
}

// ------------- single-buffer BK=64 core: high-depth kernels ---------------
// LDS: As/Bs each [128][64] ushort (16 KB each, 32 KB -> capacity 5/CU).
__device__ __forceinline__ void gemm128_core_sb64(
    const ushort* __restrict__ A, const ushort* __restrict__ B,
    int lda, int ldb, int m0, int n0, int kIters,
    ushort* As, ushort* Bs, f32x4 acc[4][4])
{
    const int tid  = threadIdx.x;
    const int lane = tid & 63, wave = tid >> 6;
    const int wm = (wave >> 1) * 64, wn = (wave & 1) * 64;
    const int quad = lane >> 4, l16 = lane & 15;
    const int srow8 = lane >> 3;
    const int gchk  = (lane & 7) ^ srow8;      // pre-swizzled global chunk
    const ushort* ag = A + (size_t)(m0 + wave * 32 + srow8) * lda + gchk * 8;
    const ushort* bg = B + (size_t)(n0 + wave * 32 + srow8) * ldb + gchk * 8;
    const int p0 = quad ^ (l16 & 7);           // kk=0 read chunk; kk=1 is p0^4

    for (int kt = 0; kt < kIters; ++kt) {
        const int k0 = kt * 64;
#pragma unroll
        for (int s = 0; s < 4; ++s) {
            async_load16(ag + k0 + (size_t)(s * 8) * lda,
                         As + (wave * 32 + s * 8) * 64);
            async_load16(bg + k0 + (size_t)(s * 8) * ldb,
                         Bs + (wave * 32 + s * 8) * 64);
        }
        __syncthreads();
#pragma unroll
        for (int kk = 0; kk < 2; ++kk) {
            const int poff = (p0 ^ (kk << 2)) * 8;
            bf16x8 aF[4], bF[4];
#pragma unroll
            for (int i = 0; i < 4; ++i)
                aF[i] = *(const bf16x8*)(As + (wm + i * 16 + l16) * 64 + poff);
#pragma unroll
            for (int j = 0; j < 4; ++j)
                bF[j] = *(const bf16x8*)(Bs + (wn + j * 16 + l16) * 64 + poff);
#pragma unroll
            for (int i = 0; i < 4; ++i)
#pragma unroll
                for (int j = 0; j < 4; ++j)
                    acc[i][j] = __builtin_amdgcn_mfma_f32_16x16x32_bf16(aF[i], bF[j], acc[i][j], 0, 0, 0);
        }
        __syncthreads();
    }
}

// ------------- double-buffered BK=64 core: scores/pv ----------------------
// LDS: As/Bs each [2][128][64] ushort (32 KB each, 64 KB total).
__device__ __forceinline__ void gemm128_core_db64(
    const ushort* __restrict__ A, const ushort* __restrict__ B,
    int lda, int ldb, int m0, int n0, int kIters,
    ushort* As, ushort* Bs, f32x4 acc[4][4])
{
    const int tid  = threadIdx.x;
    const int lane = tid & 63, wave = tid >> 6;
    const int wm = (wave >> 1) * 64, wn = (wave & 1) * 64;
    const int quad = lane >> 4, l16 = lane & 15;
    const int srow8 = lane >> 3;
    const int gchk  = (lane & 7) ^ srow8;
    const ushort* ag = A + (size_t)(m0 + wave * 32 + srow8) * lda + gchk * 8;
    const ushort* bg = B + (size_t)(n0 + wave * 32 + srow8) * ldb + gchk * 8;
    const int p0 = quad ^ (l16 & 7);

#define STAGE64(K0, NB) do {                                            \
        _Pragma("unroll")                                               \
        for (int s = 0; s < 4; ++s) {                                   \
            async_load16(ag + (K0) + (size_t)(s * 8) * lda,             \
                         As + (NB) + (wave * 32 + s * 8) * 64);         \
            async_load16(bg + (K0) + (size_t)(s * 8) * ldb,             \
                         Bs + (NB) + (wave * 32 + s * 8) * 64);         \
        }                                                               \
    } while (0)

    STAGE64(0, 0);
    __syncthreads();

    int cur = 0;
    for (int kt = 0; kt < kIters; ++kt) {
        if (kt + 1 < kIters) STAGE64((kt + 1) * 64, (cur ^ 1) * 8192);
        const ushort* as = As + cur * 8192;
        const ushort* bs = Bs + cur * 8192;
#pragma unroll
        for (int kk = 0; kk < 2; ++kk) {
            const int poff = (p0 ^ (kk << 2)) * 8;
            bf16x8 aF[4], bF[4];
#pragma unroll
            for (int i = 0; i < 4; ++i)
                aF[i] = *(const bf16x8*)(as + (wm + i * 16 + l16) * 64 + poff);
#pragma unroll
            for (int j = 0; j < 4; ++j)
                bF[j] = *(const bf16x8*)(bs + (wn + j * 16 + l16) * 64 + poff);
#pragma unroll
            for (int i = 0; i < 4; ++i)
#pragma unroll
                for (int j = 0; j < 4; ++j)
                    acc[i][j] = __builtin_amdgcn_mfma_f32_16x16x32_bf16(aF[i], bF[j], acc[i][j], 0, 0, 0);
        }
        __syncthreads();
        cur ^= 1;
    }
#undef STAGE64
}

#define ACC_INIT4(acc) \
    _Pragma("unroll") for (int i = 0; i < 4; ++i) \
    _Pragma("unroll") for (int j = 0; j < 4; ++j) \
    _Pragma("unroll") for (int r = 0; r < 4; ++r) acc[i][j][r] = 0.0f;

// QKV + RoPE, z-split. grid (64, 8, 3). sb64 core.
__global__ __launch_bounds__(256) void qkv_rope_kernel(
    const ushort* __restrict__ xb, const ushort* __restrict__ wq,
    const ushort* __restrict__ wk, const ushort* __restrict__ wv,
    const float2* __restrict__ cs,
    ushort* __restrict__ Qr, ushort* __restrict__ Kr, ushort* __restrict__ VT)
{
    __shared__ __attribute__((aligned(16))) ushort As[128 * 64];
    __shared__ __attribute__((aligned(16))) ushort Bs[128 * 64];
    const int m0 = blockIdx.x * 128;
    const int n0 = blockIdx.y * 128;
    const int z  = blockIdx.z;
    const ushort* W = (z == 0) ? wq : (z == 1) ? wk : wv;

    f32x4 acc[4][4];
    ACC_INIT4(acc)
    gemm128_core_sb64(xb, W, 1024, 1024, m0, n0, 16, As, Bs, acc);

    const int lane = threadIdx.x & 63, wave = threadIdx.x >> 6;
    const int wm = (wave >> 1) * 64, wn = (wave & 1) * 64;
    const int quad = lane >> 4, l16 = lane & 15;

    if (z < 2) {
        ushort* out = (z == 0) ? Qr : Kr;
#pragma unroll
        for (int j = 0; j < 4; ++j) {
            const int n = n0 + wn + j * 16 + l16;
            const int iidx = n >> 1;
            const bool odd = n & 1;
#pragma unroll
            for (int i = 0; i < 4; ++i) {
                const int mbase = m0 + wm + i * 16 + quad * 4;
                const int pos0  = mbase & 2047;
                const float2* csp = cs + (size_t)pos0 * 512 + iidx;
#pragma unroll
                for (int r = 0; r < 4; ++r) {
                    const float2 sc = csp[(size_t)r * 512]; // (cos, sin) at pos0+r
                    float v = acc[i][j][r];
                    float p = __shfl_xor(v, 1);   // partner column n^1, same row
                    float o = odd ? (v * sc.x - p * sc.y) : (v * sc.x + p * sc.y);
                    out[(size_t)(mbase + r) * 1024 + n] = f2bf(o);
                }
            }
        }
    } else {
        // V transposed: VT[b][n][pos]; 4 consecutive pos per quad -> ushort4
#pragma unroll
        for (int i = 0; i < 4; ++i) {
            const int mbase = m0 + wm + i * 16 + quad * 4;
            const int b = mbase >> 11, pos0 = mbase & 2047;
#pragma unroll
            for (int j = 0; j < 4; ++j) {
                const int n = n0 + wn + j * 16 + l16;
                ushort4 o;
                o.x = f2bf(acc[i][j][0]); o.y = f2bf(acc[i][j][1]);
                o.z = f2bf(acc[i][j][2]); o.w = f2bf(acc[i][j][3]);
                *(ushort4*)(VT + ((size_t)b * 1024 + n) * 2048 + pos0) = o;
            }
        }
    }
}

// scores: grid (16, 16, 4); lower tiles only; S fp32 scaled 1/32. db64 core.
__global__ __launch_bounds__(256) void scores_kernel(
    const ushort* __restrict__ Qr, const ushort* __restrict__ Kr,
    float* __restrict__ S)
{
    const int m0 = blockIdx.x * 128;
    const int n0 = blockIdx.y * 128;
    if (n0 > m0 + 127) return;
    const int b = blockIdx.z;
    __shared__ __attribute__((aligned(16))) ushort As[2 * 128 * 64];
    __shared__ __attribute__((aligned(16))) ushort Bs[2 * 128 * 64];
    const ushort* A = Qr + (size_t)b * 2048 * 1024;
    const ushort* B = Kr + (size_t)b * 2048 * 1024;
    float* Sb = S + (size_t)b * 2048 * 2048;

    f32x4 acc[4][4];
    ACC_INIT4(acc)
    gemm128_core_db64(A, B, 1024, 1024, m0, n0, 16, As, Bs, acc);

    const int lane = threadIdx.x & 63, wave = threadIdx.x >> 6;
    const int wm = (wave >> 1) * 64, wn = (wave & 1) * 64;
    const int quad = lane >> 4, l16 = lane & 15;
#pragma unroll
    for (int i = 0; i < 4; ++i)
#pragma unroll
        for (int j = 0; j < 4; ++j) {
            const int n = n0 + wn + j * 16 + l16;
#pragma unroll
            for (int r = 0; r < 4; ++r) {
                const int m = m0 + wm + i * 16 + quad * 4 + r;
                Sb[(size_t)m * 2048 + n] = acc[i][j][r] * 0.03125f;
            }
        }
}

// Row softmax, register-staged, wave-parallel reduction (3 barriers).
// Reads clipped to nvalid; writes clipped to roundup(row+1,128).
__global__ __launch_bounds__(256) void softmax_kernel(
    const float* __restrict__ S, ushort* __restrict__ P)
{
    __shared__ float red[4];
    const int row = blockIdx.x, tid = threadIdx.x, b = blockIdx.y;
    const int lane = tid & 63, wave = tid >> 6;
    const float* s = S + ((size_t)b * 2048 + row) * 2048;
    ushort*      p = P + ((size_t)b * 2048 + row) * 2048;
    const int nvalid = row + 1;
    const int wlimit = (row & ~127) + 128;
    const int j0 = tid * 8;

    float v[8] = {0.0f, 0.0f, 0.0f, 0.0f, 0.0f, 0.0f, 0.0f, 0.0f};
    if (j0 < nvalid) {
        float4 f0 = *(const float4*)(s + j0);
        v[0]=f0.x; v[1]=f0.y; v[2]=f0.z; v[3]=f0.w;
    }
    if (j0 + 4 < nvalid) {
        float4 f1 = *(const float4*)(s + j0 + 4);
        v[4]=f1.x; v[5]=f1.y; v[6]=f1.z; v[7]=f1.w;
    }

    float mx = -3.402823466e38f;
#pragma unroll
    for (int u = 0; u < 8; ++u) if (j0 + u < nvalid) mx = fmaxf(mx, v[u]);
#pragma unroll
    for (int d = 1; d < 64; d <<= 1) mx = fmaxf(mx, __shfl_xor(mx, d));
    if (lane == 0) red[wave] = mx;
    __syncthreads();
    mx = fmaxf(fmaxf(red[0], red[1]), fmaxf(red[2], red[3]));

    float sum = 0.0f;
#pragma unroll
    for (int u = 0; u < 8; ++u) {
        v[u] = (j0 + u < nvalid) ? __expf(v[u] - mx) : 0.0f;
        sum += v[u];
    }
#pragma unroll
    for (int d = 1; d < 64; d <<= 1) sum += __shfl_xor(sum, d);
    __syncthreads();                 // all reads of red done before overwrite
    if (lane == 0) red[wave] = sum;
    __syncthreads();
    const float inv = 1.0f / (red[0] + red[1] + red[2] + red[3]);

    if (j0 < wlimit) {
        ushort o[8];
#pragma unroll
        for (int u = 0; u < 8; ++u) o[u] = f2bf(v[u] * inv);
        *(int4*)(p + j0) = *(const int4*)o;
    }
}

// pv: grid (16, 8, 4); causal k-limit; db64 core; m-tile interleave.
__global__ __launch_bounds__(256) void pv_kernel(
    const ushort* __restrict__ P, const ushort* __restrict__ VT,
    float* __restrict__ out)
{
    __shared__ __attribute__((aligned(16))) ushort As[2 * 128 * 64];
    __shared__ __attribute__((aligned(16))) ushort Bs[2 * 128 * 64];
    const int x  = blockIdx.x;
    const int mt = (x & 1) ? (15 - (x >> 1)) : (x >> 1);  // 0,15,1,14,...
    const int m0 = mt * 128;
    const int n0 = blockIdx.y * 128;
    const int b  = blockIdx.z;
    const ushort* A = P + (size_t)b * 2048 * 2048;
    const ushort* B = VT + (size_t)b * 1024 * 2048;
    const int kIters = (m0 + 128) / 64;   // causal: P[m][k]=0 for k>m

    f32x4 acc[4][4];
    ACC_INIT4(acc)
    gemm128_core_db64(A, B, 2048, 2048, m0, n0, kIters, As, Bs, acc);

    const int lane = threadIdx.x & 63, wave = threadIdx.x >> 6;
    const int wm = (wave >> 1) * 64, wn = (wave & 1) * 64;
    const int quad = lane >> 4, l16 = lane & 15;
#pragma unroll
    for (int i = 0; i < 4; ++i)
#pragma unroll
        for (int j = 0; j < 4; ++j) {
            const int n = n0 + wn + j * 16 + l16;
#pragma unroll
            for (int r = 0; r < 4; ++r) {
                const int m = m0 + wm + i * 16 + quad * 4 + r;
                out[((size_t)b * 2048 + m) * 1024 + n] = acc[i][j][r];
            }
        }
}

extern "C" void kernel_launch(void* const* d_in, const int* in_sizes, int n_in,
                              void* d_out, int out_size, void* d_ws, size_t ws_size,
                              hipStream_t stream) {
    const float* x  = (const float*)d_in[0];
    const float* wq = (const float*)d_in[1];
    const float* wk = (const float*)d_in[2];
    const float* wv = (const float*)d_in[3];

    const size_t MiB = 1024 * 1024;
    char* ws = (char*)d_ws;
    ushort* xb  = (ushort*)(ws);              //  16 MiB [8192][1024] bf16
    ushort* wqb = (ushort*)(ws +  16 * MiB);  //   2 MiB
    ushort* wkb = (ushort*)(ws +  18 * MiB);  //   2 MiB
    ushort* wvb = (ushort*)(ws +  20 * MiB);  //   2 MiB
    ushort* Qr  = (ushort*)(ws +  22 * MiB);  //  16 MiB [4][2048][1024] bf16
    ushort* Kr  = (ushort*)(ws +  38 * MiB);  //  16 MiB
    ushort* VT  = (ushort*)(ws +  54 * MiB);  //  16 MiB [4][1024][2048] bf16
    float*  S   = (float* )(ws +  70 * MiB);  //  64 MiB [4][2048][2048] f32
    ushort* P   = (ushort*)(ws + 134 * MiB);  //  32 MiB [4][2048][2048] bf16
    float2* cs  = (float2*)(ws + 166 * MiB);  //   8 MiB [2048][512] (cos,sin) f32
    float*  out = (float*)d_out;              // ws use: 174 MiB (256 avail)

    cvt_all_kernel <<<dim3(8192, 5),   256, 0, stream>>>(x, wq, wk, wv, xb, wqb, wkb, wvb, cs);
    qkv_rope_kernel<<<dim3(64, 8, 3),  256, 0, stream>>>(xb, wqb, wkb, wvb, cs, Qr, Kr, VT);
    scores_kernel  <<<dim3(16, 16, 4), 256, 0, stream>>>(Qr, Kr, S);
    softmax_kernel <<<dim3(2048, 4),   256, 0, stream>>>(S, P);
    pv_kernel      <<<dim3(16, 8, 4),  256, 0, stream>>>(P, VT, out);
}